// Round 14
// baseline (337.570 us; speedup 1.0000x reference)
//
#include <hip/hip_runtime.h>
#include <hip/hip_fp16.h>

#define LAT 64
#define ELLC 64       // ELL row capacity (deg ~ Poisson(32); overflow handled)
#define RB 256        // rows per bucket
#define RBSH 8
#define MAXBUK 512    // static LDS sizing; nbuk = ceil(N/256) = 391 for N=100k
#define RPT 8         // undirected edges cached per thread (256 x 1024 x 8 >= E)

// ---------- phase 1: bin directed edges by row-bucket (single edge read) -----
__global__ void __launch_bounds__(1024)
bin_k(const int* __restrict__ eu, const int* __restrict__ ei,
      int* __restrict__ gcur, unsigned int* __restrict__ bbuf,
      int2* __restrict__ ovf, int* __restrict__ ovfc,
      int E, int U, int nbuk, int cap, int ovf_cap) {
    __shared__ int lcnt[MAXBUK];
    __shared__ int lbase[MAXBUK];
    for (int i = threadIdx.x; i < nbuk; i += blockDim.x) lcnt[i] = 0;
    __syncthreads();
    int tid = blockIdx.x * blockDim.x + threadIdx.x;
    int stride = gridDim.x * blockDim.x;
    int ru[RPT], rc[RPT];
    int ne = 0;
#pragma unroll
    for (int k = 0; k < RPT; ++k) {
        int d = tid + k * stride;
        if (d < E) {
            int u = eu[d], c = ei[d] + U;
            ru[k] = u; rc[k] = c; ne = k + 1;
            atomicAdd(&lcnt[u >> RBSH], 1);
            atomicAdd(&lcnt[c >> RBSH], 1);
        }
    }
    __syncthreads();
    for (int b = threadIdx.x; b < nbuk; b += blockDim.x)
        lbase[b] = atomicAdd(&gcur[b], lcnt[b]);      // global reservation
    __syncthreads();
#pragma unroll
    for (int k = 0; k < RPT; ++k) {
        if (k < ne) {
            int u = ru[k], c = rc[k];
            int b = u >> RBSH;
            int pos = atomicAdd(&lbase[b], 1);
            if (pos < cap)
                bbuf[(size_t)b * cap + pos] = ((unsigned)(u & (RB - 1)) << 17) | (unsigned)c;
            else { int o = atomicAdd(ovfc, 1); if (o < ovf_cap) ovf[o] = make_int2(u, c); }
            b = c >> RBSH;
            pos = atomicAdd(&lbase[b], 1);
            if (pos < cap)
                bbuf[(size_t)b * cap + pos] = ((unsigned)(c & (RB - 1)) << 17) | (unsigned)u;
            else { int o = atomicAdd(ovfc, 1); if (o < ovf_cap) ovf[o] = make_int2(c, u); }
        }
    }
}

// ---------- phase 2: per-bucket ELL build + dinv + fused y0 init ----------
__global__ void __launch_bounds__(1024)
build_k(const unsigned int* __restrict__ bbuf, const int* __restrict__ gcur,
        int* __restrict__ cnt, int* __restrict__ colE, float* __restrict__ dinv,
        const float* __restrict__ ue, const float* __restrict__ ie,
        __half* __restrict__ y0,
        int2* __restrict__ rovf, int* __restrict__ rovfc,
        int N, int U, int cap, int rovf_cap) {
    __shared__ int lcnt[RB];
    __shared__ float ldv[RB];
    int b = blockIdx.x;
    for (int i = threadIdx.x; i < RB; i += blockDim.x) lcnt[i] = 0;
    __syncthreads();
    int nb = min(gcur[b], cap);
    const unsigned int* src = bbuf + (size_t)b * cap;
    for (int e = threadIdx.x; e < nb; e += blockDim.x) {
        unsigned w = __builtin_nontemporal_load(src + e);   // streamed once
        int r7 = (int)(w >> 17);
        int c = (int)(w & 0x1FFFF);
        int pos = atomicAdd(&lcnt[r7], 1);
        int r = (b << RBSH) + r7;
        if (pos < ELLC) colE[(size_t)r * ELLC + pos] = c;   // 64KB L2 window
        else { int o = atomicAdd(rovfc, 1); if (o < rovf_cap) rovf[o] = make_int2(r, c); }
    }
    __syncthreads();
    for (int i = threadIdx.x; i < RB; i += blockDim.x) {
        int r = (b << RBSH) + i;
        if (r < N) {
            int d = lcnt[i];
            cnt[r] = d;
            float dv = (d > 0) ? rsqrtf((float)d) : 0.0f;
            dinv[r] = dv;            // spill rows fixed in fix_k
            ldv[i] = dv;
        }
    }
    __syncthreads();
    int r0 = b << RBSH;
    int rows = min(RB, N - r0);
    for (int w = threadIdx.x; w < rows * 32; w += blockDim.x) {
        int i = w >> 5, j = w & 31;
        int r = r0 + i;
        const float* s = (r < U) ? (ue + (size_t)r * LAT) : (ie + (size_t)(r - U) * LAT);
        float2 f = ((const float2*)s)[j];
        ((__half2*)y0)[(size_t)r * 32 + j] = __floats2half2_rn(ldv[i] * f.x, ldv[i] * f.y);
    }
}

// bin-phase spill fix-up + dinv + y0 repair (expected 0 entries). Single block.
__global__ void __launch_bounds__(1024)
fix_k(const int2* __restrict__ ovf, const int* __restrict__ ovfc,
      int* __restrict__ cnt, int* __restrict__ colE, float* __restrict__ dinv,
      const float* __restrict__ ue, const float* __restrict__ ie,
      __half* __restrict__ y0,
      int2* __restrict__ rovf, int* __restrict__ rovfc,
      int ovf_cap, int rovf_cap, int U) {
    int n = min(*ovfc, ovf_cap);
    for (int i = threadIdx.x; i < n; i += blockDim.x) {
        int r = ovf[i].x, c = ovf[i].y;
        int pos = atomicAdd(&cnt[r], 1);
        if (pos < ELLC) colE[(size_t)r * ELLC + pos] = c;
        else { int o = atomicAdd(rovfc, 1); if (o < rovf_cap) rovf[o] = make_int2(r, c); }
    }
    __syncthreads();
    for (int i = threadIdx.x; i < n; i += blockDim.x) {
        int r = ovf[i].x;
        int d = cnt[r];
        dinv[r] = (d > 0) ? rsqrtf((float)d) : 0.0f;
    }
    __syncthreads();
    for (int w = threadIdx.x; w < n * LAT; w += blockDim.x) {
        int o = w >> 6, dim = w & 63;
        int r = ovf[o].x;
        float e = (r < U) ? ue[(size_t)r * LAT + dim] : ie[(size_t)(r - U) * LAT + dim];
        y0[(size_t)r * LAT + dim] = __float2half(dinv[r] * e);
    }
}

// ---------- propagation core: straight-line K-quad gather (R13) ----------
template<int K>
__device__ __forceinline__ void gather_acc(const uint4* __restrict__ y16,
                                           int call, int g, int t, int len,
                                           float2 acc[4]) {
    uint4 v[K];
#pragma unroll
    for (int q = 0; q < K; ++q) {
        int c = __shfl(call, (q << 3) + g);
        v[q] = y16[(size_t)c * 8 + t];                 // y: cacheable (reused)
    }
#pragma unroll
    for (int q = 0; q < K; ++q) {
        if (q < K - 1 || ((q << 3) + g) < len) {
            const __half2* h = (const __half2*)&v[q];
#pragma unroll
            for (int d = 0; d < 4; ++d) {
                float2 f = __half22float2(h[d]);
                acc[d].x += f.x; acc[d].y += f.y;
            }
        }
    }
}

// Waves [0,N): row path. Stream-only operands (cnt, colE) are loaded
// NON-TEMPORAL so they don't evict y rows from the 4MB per-XCD L2 —
// colE alone streams 25.6MB/dispatch with zero reuse (R13: FETCH 109MB).
// Waves [N, N+2B): query gather qacc (+)= x = yin/dinv.
__global__ void __launch_bounds__(256, 4)
prop_h_k(const int* __restrict__ cnt, const int* __restrict__ colE,
         const float* __restrict__ dinv, const __half* __restrict__ yin,
         __half* __restrict__ yout,
         const int* __restrict__ users, const int* __restrict__ items,
         float* __restrict__ qacc,
         const int2* __restrict__ rovf, const int* __restrict__ rovfc,
         int rovf_cap, int B, int U, int first, int N) {
    int wave = blockIdx.x * (blockDim.x >> 6) + (threadIdx.x >> 6);
    int lane = threadIdx.x & 63;
    if (wave >= N) {
        int qw = wave - N;
        if (qw >= 2 * B) return;
        int node = (qw < B) ? users[qw] : (items[qw - B] + U);
        float di = dinv[node];
        float r = (di > 0.0f) ? (1.0f / di) : 0.0f;
        float v = __half2float(yin[(size_t)node * LAT + lane]) * r;
        if (first) qacc[qw * LAT + lane] = v;
        else       qacc[qw * LAT + lane] += v;
        return;
    }
    int g = lane >> 3;        // group 0..7: neighbor j = 8*q + g
    int t = lane & 7;         // 16B chunk: dims 8t..8t+7
    int len = min(__builtin_nontemporal_load(cnt + wave), ELLC);
    const int* cp = colE + (size_t)wave * ELLC;
    int lm0 = max(len - 1, 0);
    int call = __builtin_nontemporal_load(cp + min(lane, lm0));  // 256B stream
    const uint4* y16 = (const uint4*)yin;

    float2 acc[4];
#pragma unroll
    for (int d = 0; d < 4; ++d) acc[d] = make_float2(0.f, 0.f);

    int nb = (len + 7) >> 3;              // wave-uniform 0..8
    switch (nb) {
        case 1: gather_acc<1>(y16, call, g, t, len, acc); break;
        case 2: gather_acc<2>(y16, call, g, t, len, acc); break;
        case 3: gather_acc<3>(y16, call, g, t, len, acc); break;
        case 4: gather_acc<4>(y16, call, g, t, len, acc); break;
        case 5: gather_acc<5>(y16, call, g, t, len, acc); break;
        case 6: gather_acc<6>(y16, call, g, t, len, acc); break;
        case 7: gather_acc<7>(y16, call, g, t, len, acc); break;
        case 8: gather_acc<8>(y16, call, g, t, len, acc); break;
        default: break;                    // len==0
    }
    // inline overflow epilogue (rovf static across layers; expected empty)
    int novf = min(*rovfc, rovf_cap);
    for (int o = 0; o < novf; ++o) {
        int2 eo = rovf[o];
        if (eo.x == wave && g == 0) {
            uint4 vv = y16[(size_t)eo.y * 8 + t];
            const __half2* h = (const __half2*)&vv;
#pragma unroll
            for (int d = 0; d < 4; ++d) { float2 f = __half22float2(h[d]); acc[d].x += f.x; acc[d].y += f.y; }
        }
    }
#pragma unroll
    for (int d = 0; d < 4; ++d) {
        acc[d].x += __shfl_xor(acc[d].x, 8);  acc[d].y += __shfl_xor(acc[d].y, 8);
        acc[d].x += __shfl_xor(acc[d].x, 16); acc[d].y += __shfl_xor(acc[d].y, 16);
        acc[d].x += __shfl_xor(acc[d].x, 32); acc[d].y += __shfl_xor(acc[d].y, 32);
    }
    if (g == 0) {
        float di = dinv[wave];
        float f = di * di;
        __half2 o[4];
#pragma unroll
        for (int d = 0; d < 4; ++d)
            o[d] = __floats2half2_rn(f * acc[d].x, f * acc[d].y);
        ((uint4*)yout)[(size_t)wave * 8 + t] = *(const uint4*)o;
    }
}

// final: qacc += x4 at queried nodes, then gamma = dot/25
__global__ void final_k(const float* __restrict__ qacc, const __half* __restrict__ y4,
                        const float* __restrict__ dinv,
                        const int* __restrict__ users, const int* __restrict__ items,
                        float* __restrict__ out, int B, int U) {
    int wave = blockIdx.x * (blockDim.x >> 6) + (threadIdx.x >> 6);
    int lane = threadIdx.x & 63;
    if (wave >= B) return;
    int un = users[wave];
    int in = items[wave] + U;
    float du = dinv[un], di = dinv[in];
    float ru = (du > 0.f) ? (1.f / du) : 0.f;
    float ri = (di > 0.f) ? (1.f / di) : 0.f;
    float au = qacc[wave * LAT + lane] + __half2float(y4[(size_t)un * LAT + lane]) * ru;
    float ai = qacc[(wave + B) * LAT + lane] + __half2float(y4[(size_t)in * LAT + lane]) * ri;
    float p = au * ai;
#pragma unroll
    for (int off = 32; off > 0; off >>= 1) p += __shfl_down(p, off);
    if (lane == 0) out[wave] = p * (1.0f / 25.0f);
}

extern "C" void kernel_launch(void* const* d_in, const int* in_sizes, int n_in,
                              void* d_out, int out_size, void* d_ws, size_t ws_size,
                              hipStream_t stream) {
    const float* ue = (const float*)d_in[0];
    const float* ie = (const float*)d_in[1];
    const int* edge = (const int*)d_in[2];
    const int* users = (const int*)d_in[3];
    const int* items = (const int*)d_in[4];

    const int U = in_sizes[0] / LAT;
    const int I = in_sizes[1] / LAT;
    const int N = U + I;
    const int E = in_sizes[2] / 2;
    const int B = in_sizes[3];
    const int* eu = edge;
    const int* ei = edge + E;

    const int nbuk = (N + RB - 1) / RB;                    // 391 for N=100k
    const int cap = ((2 * E / nbuk) * 5 / 4 + 255) & ~255; // ~25% slack

    char* ws = (char*)d_ws;
    size_t off = 0;
    auto alloc = [&](size_t bytes) -> void* {
        void* p = ws + off;
        off += (bytes + 255) & ~(size_t)255;
        return p;
    };
    int*      cnt  = (int*)alloc((size_t)4 * N);
    float*    dinv = (float*)alloc((size_t)4 * N);
    int*      colE = (int*)alloc((size_t)4 * N * ELLC);     // 25.6 MB
    __half*   yA   = (__half*)alloc((size_t)2 * N * LAT);   // 12.8 MB
    __half*   yB   = (__half*)alloc((size_t)2 * N * LAT);
    float*    qacc = (float*)alloc((size_t)4 * 2 * B * LAT);
    unsigned* bbuf = (unsigned*)alloc((size_t)4 * nbuk * cap);  // ~16 MB
    size_t zoff = off;
    int*      gcur = (int*)alloc((size_t)4 * nbuk);
    int*      ovfc = (int*)alloc(256);   // [0]=bin spill, [64]=row ovf
    size_t zbytes = off - zoff;
    size_t remain = (ws_size > off + 256) ? (ws_size - off - 256) : 0;
    int ovf_cap = (int)min((size_t)131072, remain / (2 * sizeof(int2)));
    int2* ovf  = (int2*)alloc((size_t)ovf_cap * sizeof(int2));
    int2* rovf = (int2*)alloc((size_t)ovf_cap * sizeof(int2));
    int* rovfc = ovfc + 64;

    hipError_t _e = hipMemsetAsync(gcur, 0, zbytes, stream); (void)_e;

    const int tb = 256;

    bin_k<<<256, 1024, 0, stream>>>(eu, ei, gcur, bbuf, ovf, ovfc, E, U, nbuk, cap, ovf_cap);
    build_k<<<nbuk, 1024, 0, stream>>>(bbuf, gcur, cnt, colE, dinv, ue, ie, yA,
                                       rovf, rovfc, N, U, cap, ovf_cap);
    fix_k<<<1, 1024, 0, stream>>>(ovf, ovfc, cnt, colE, dinv, ue, ie, yA,
                                  rovf, rovfc, ovf_cap, ovf_cap, U);

    const int wpb = tb / 64;
    int pgrid = (N + 2 * B + wpb - 1) / wpb;   // row waves + fused query waves

    __half* yin = yA;
    __half* yout = yB;
    for (int layer = 0; layer < 4; ++layer) {
        prop_h_k<<<pgrid, tb, 0, stream>>>(cnt, colE, dinv, yin, yout,
                                           users, items, qacc, rovf, rovfc,
                                           ovf_cap, B, U, layer == 0 ? 1 : 0, N);
        __half* tmp = yin; yin = yout; yout = tmp;
    }

    final_k<<<(B + wpb - 1) / wpb, tb, 0, stream>>>(qacc, yin, dinv, users, items,
                                                    (float*)d_out, B, U);
}

// Round 15
// 311.337 us; speedup vs baseline: 1.0843x; 1.0843x over previous
//
#include <hip/hip_runtime.h>
#include <hip/hip_fp16.h>

#define LAT 64
#define ELLC 64       // ELL row capacity (deg ~ Poisson(32); overflow handled)
#define RB 256        // rows per bucket
#define RBSH 8
#define MAXBUK 512    // static LDS sizing; nbuk = ceil(N/256) = 391 for N=100k
#define RPT 8         // undirected edges cached per thread (256 x 1024 x 8 >= E)

// ---------- phase 1: bin directed edges by row-bucket (single edge read) -----
// Each thread caches <=RPT undirected edges (eu,ei pairs) in registers and
// emits BOTH directed records — edge arrays read once. Global atomics: one
// reservation per (block,bucket) ~= 100k.
// Packed word: (r & 255) << 17 | c   (needs N <= 131072).
__global__ void __launch_bounds__(1024)
bin_k(const int* __restrict__ eu, const int* __restrict__ ei,
      int* __restrict__ gcur, unsigned int* __restrict__ bbuf,
      int2* __restrict__ ovf, int* __restrict__ ovfc,
      int E, int U, int nbuk, int cap, int ovf_cap) {
    __shared__ int lcnt[MAXBUK];
    __shared__ int lbase[MAXBUK];
    for (int i = threadIdx.x; i < nbuk; i += blockDim.x) lcnt[i] = 0;
    __syncthreads();
    int tid = blockIdx.x * blockDim.x + threadIdx.x;
    int stride = gridDim.x * blockDim.x;
    int ru[RPT], rc[RPT];
    int ne = 0;
#pragma unroll
    for (int k = 0; k < RPT; ++k) {
        int d = tid + k * stride;
        if (d < E) {
            int u = eu[d], c = ei[d] + U;
            ru[k] = u; rc[k] = c; ne = k + 1;
            atomicAdd(&lcnt[u >> RBSH], 1);   // user-side row
            atomicAdd(&lcnt[c >> RBSH], 1);   // item-side row
        }
    }
    __syncthreads();
    for (int b = threadIdx.x; b < nbuk; b += blockDim.x)
        lbase[b] = atomicAdd(&gcur[b], lcnt[b]);      // global reservation
    __syncthreads();
#pragma unroll
    for (int k = 0; k < RPT; ++k) {
        if (k < ne) {
            int u = ru[k], c = rc[k];
            int b = u >> RBSH;
            int pos = atomicAdd(&lbase[b], 1);
            if (pos < cap)
                bbuf[(size_t)b * cap + pos] = ((unsigned)(u & (RB - 1)) << 17) | (unsigned)c;
            else { int o = atomicAdd(ovfc, 1); if (o < ovf_cap) ovf[o] = make_int2(u, c); }
            b = c >> RBSH;
            pos = atomicAdd(&lbase[b], 1);
            if (pos < cap)
                bbuf[(size_t)b * cap + pos] = ((unsigned)(c & (RB - 1)) << 17) | (unsigned)u;
            else { int o = atomicAdd(ovfc, 1); if (o < ovf_cap) ovf[o] = make_int2(c, u); }
        }
    }
}

// ---------- phase 2: per-bucket ELL build + dinv + fused y0 init ----------
__global__ void __launch_bounds__(1024)
build_k(const unsigned int* __restrict__ bbuf, const int* __restrict__ gcur,
        int* __restrict__ cnt, int* __restrict__ colE, float* __restrict__ dinv,
        const float* __restrict__ ue, const float* __restrict__ ie,
        __half* __restrict__ y0,
        int2* __restrict__ rovf, int* __restrict__ rovfc,
        int N, int U, int cap, int rovf_cap) {
    __shared__ int lcnt[RB];
    __shared__ float ldv[RB];
    int b = blockIdx.x;
    for (int i = threadIdx.x; i < RB; i += blockDim.x) lcnt[i] = 0;
    __syncthreads();
    int nb = min(gcur[b], cap);
    const unsigned int* src = bbuf + (size_t)b * cap;
    for (int e = threadIdx.x; e < nb; e += blockDim.x) {
        unsigned w = src[e];
        int r7 = (int)(w >> 17);
        int c = (int)(w & 0x1FFFF);
        int pos = atomicAdd(&lcnt[r7], 1);
        int r = (b << RBSH) + r7;
        if (pos < ELLC) colE[(size_t)r * ELLC + pos] = c;   // 64KB L2 window
        else { int o = atomicAdd(rovfc, 1); if (o < rovf_cap) rovf[o] = make_int2(r, c); }
    }
    __syncthreads();
    for (int i = threadIdx.x; i < RB; i += blockDim.x) {
        int r = (b << RBSH) + i;
        if (r < N) {
            int d = lcnt[i];
            cnt[r] = d;
            float dv = (d > 0) ? rsqrtf((float)d) : 0.0f;
            dinv[r] = dv;            // spill rows fixed in fix_k
            ldv[i] = dv;
        }
    }
    __syncthreads();
    // fused y0 = fp16(dinv * e0) for this bucket's rows (coalesced float2)
    int r0 = b << RBSH;
    int rows = min(RB, N - r0);
    for (int w = threadIdx.x; w < rows * 32; w += blockDim.x) {
        int i = w >> 5, j = w & 31;
        int r = r0 + i;
        const float* s = (r < U) ? (ue + (size_t)r * LAT) : (ie + (size_t)(r - U) * LAT);
        float2 f = ((const float2*)s)[j];
        ((__half2*)y0)[(size_t)r * 32 + j] = __floats2half2_rn(ldv[i] * f.x, ldv[i] * f.y);
    }
}

// bin-phase spill fix-up + dinv + y0 repair (expected 0 entries). Single block;
// __syncthreads between phases so final cnt is seen.
__global__ void __launch_bounds__(1024)
fix_k(const int2* __restrict__ ovf, const int* __restrict__ ovfc,
      int* __restrict__ cnt, int* __restrict__ colE, float* __restrict__ dinv,
      const float* __restrict__ ue, const float* __restrict__ ie,
      __half* __restrict__ y0,
      int2* __restrict__ rovf, int* __restrict__ rovfc,
      int ovf_cap, int rovf_cap, int U) {
    int n = min(*ovfc, ovf_cap);
    for (int i = threadIdx.x; i < n; i += blockDim.x) {
        int r = ovf[i].x, c = ovf[i].y;
        int pos = atomicAdd(&cnt[r], 1);
        if (pos < ELLC) colE[(size_t)r * ELLC + pos] = c;
        else { int o = atomicAdd(rovfc, 1); if (o < rovf_cap) rovf[o] = make_int2(r, c); }
    }
    __syncthreads();
    for (int i = threadIdx.x; i < n; i += blockDim.x) {
        int r = ovf[i].x;
        int d = cnt[r];
        dinv[r] = (d > 0) ? rsqrtf((float)d) : 0.0f;
    }
    __syncthreads();
    for (int w = threadIdx.x; w < n * LAT; w += blockDim.x) {
        int o = w >> 6, dim = w & 63;
        int r = ovf[o].x;
        float e = (r < U) ? ue[(size_t)r * LAT + dim] : ie[(size_t)(r - U) * LAT + dim];
        y0[(size_t)r * LAT + dim] = __float2half(dinv[r] * e);
    }
}

// ---------- propagation core: straight-line K-quad gather ----------
// K is the wave-uniform quad count; all K gathers are issued in one branchless
// run (only the last quad needs a predicate: for q<K-1, 8q+g < len always).
template<int K>
__device__ __forceinline__ void gather_acc(const uint4* __restrict__ y16,
                                           int call, int g, int t, int len,
                                           float2 acc[4]) {
    uint4 v[K];
#pragma unroll
    for (int q = 0; q < K; ++q) {
        int c = __shfl(call, (q << 3) + g);
        v[q] = y16[(size_t)c * 8 + t];
    }
#pragma unroll
    for (int q = 0; q < K; ++q) {
        if (q < K - 1 || ((q << 3) + g) < len) {
            const __half2* h = (const __half2*)&v[q];
#pragma unroll
            for (int d = 0; d < 4; ++d) {
                float2 f = __half22float2(h[d]);
                acc[d].x += f.x; acc[d].y += f.y;
            }
        }
    }
}

// Waves [0,N): one wave per node; 8 groups x 8 lanes x 16B gathers — measured
// at the cache-fabric random-line floor (~47us; 6.4M random 64B lines).
// NOTE: plain cached loads for cnt/colE — R14 measured nontemporal hints
// REGRESS these contiguous streams (53.5us, -13%).
// Waves [N, N+2B): query gather qacc (+)= x = yin/dinv.
__global__ void __launch_bounds__(256, 4)
prop_h_k(const int* __restrict__ cnt, const int* __restrict__ colE,
         const float* __restrict__ dinv, const __half* __restrict__ yin,
         __half* __restrict__ yout,
         const int* __restrict__ users, const int* __restrict__ items,
         float* __restrict__ qacc,
         const int2* __restrict__ rovf, const int* __restrict__ rovfc,
         int rovf_cap, int B, int U, int first, int N) {
    int wave = blockIdx.x * (blockDim.x >> 6) + (threadIdx.x >> 6);
    int lane = threadIdx.x & 63;
    if (wave >= N) {
        int qw = wave - N;
        if (qw >= 2 * B) return;
        int node = (qw < B) ? users[qw] : (items[qw - B] + U);
        float di = dinv[node];
        float r = (di > 0.0f) ? (1.0f / di) : 0.0f;
        float v = __half2float(yin[(size_t)node * LAT + lane]) * r;
        if (first) qacc[qw * LAT + lane] = v;
        else       qacc[qw * LAT + lane] += v;
        return;
    }
    int g = lane >> 3;        // group 0..7: neighbor j = 8*q + g
    int t = lane & 7;         // 16B chunk: dims 8t..8t+7
    int len = min(cnt[wave], ELLC);
    const int* cp = colE + (size_t)wave * ELLC;
    int lm0 = max(len - 1, 0);
    int call = cp[min(lane, lm0)];        // one coalesced 256B col load
    const uint4* y16 = (const uint4*)yin;

    float2 acc[4];
#pragma unroll
    for (int d = 0; d < 4; ++d) acc[d] = make_float2(0.f, 0.f);

    int nb = (len + 7) >> 3;              // wave-uniform 0..8
    switch (nb) {                          // scalar branch; straight-line bodies
        case 1: gather_acc<1>(y16, call, g, t, len, acc); break;
        case 2: gather_acc<2>(y16, call, g, t, len, acc); break;
        case 3: gather_acc<3>(y16, call, g, t, len, acc); break;
        case 4: gather_acc<4>(y16, call, g, t, len, acc); break;
        case 5: gather_acc<5>(y16, call, g, t, len, acc); break;
        case 6: gather_acc<6>(y16, call, g, t, len, acc); break;
        case 7: gather_acc<7>(y16, call, g, t, len, acc); break;
        case 8: gather_acc<8>(y16, call, g, t, len, acc); break;
        default: break;                    // len==0
    }
    // inline overflow epilogue (rovf static across layers; expected empty)
    int novf = min(*rovfc, rovf_cap);
    for (int o = 0; o < novf; ++o) {
        int2 eo = rovf[o];
        if (eo.x == wave && g == 0) {
            uint4 vv = y16[(size_t)eo.y * 8 + t];
            const __half2* h = (const __half2*)&vv;
#pragma unroll
            for (int d = 0; d < 4; ++d) { float2 f = __half22float2(h[d]); acc[d].x += f.x; acc[d].y += f.y; }
        }
    }
#pragma unroll
    for (int d = 0; d < 4; ++d) {
        acc[d].x += __shfl_xor(acc[d].x, 8);  acc[d].y += __shfl_xor(acc[d].y, 8);
        acc[d].x += __shfl_xor(acc[d].x, 16); acc[d].y += __shfl_xor(acc[d].y, 16);
        acc[d].x += __shfl_xor(acc[d].x, 32); acc[d].y += __shfl_xor(acc[d].y, 32);
    }
    if (g == 0) {
        float di = dinv[wave];
        float f = di * di;
        __half2 o[4];
#pragma unroll
        for (int d = 0; d < 4; ++d)
            o[d] = __floats2half2_rn(f * acc[d].x, f * acc[d].y);
        ((uint4*)yout)[(size_t)wave * 8 + t] = *(const uint4*)o;
    }
}

// final: qacc += x4 at queried nodes, then gamma = dot/25 (fused last qgather)
__global__ void final_k(const float* __restrict__ qacc, const __half* __restrict__ y4,
                        const float* __restrict__ dinv,
                        const int* __restrict__ users, const int* __restrict__ items,
                        float* __restrict__ out, int B, int U) {
    int wave = blockIdx.x * (blockDim.x >> 6) + (threadIdx.x >> 6);
    int lane = threadIdx.x & 63;
    if (wave >= B) return;
    int un = users[wave];
    int in = items[wave] + U;
    float du = dinv[un], di = dinv[in];
    float ru = (du > 0.f) ? (1.f / du) : 0.f;
    float ri = (di > 0.f) ? (1.f / di) : 0.f;
    float au = qacc[wave * LAT + lane] + __half2float(y4[(size_t)un * LAT + lane]) * ru;
    float ai = qacc[(wave + B) * LAT + lane] + __half2float(y4[(size_t)in * LAT + lane]) * ri;
    float p = au * ai;
#pragma unroll
    for (int off = 32; off > 0; off >>= 1) p += __shfl_down(p, off);
    if (lane == 0) out[wave] = p * (1.0f / 25.0f);
}

extern "C" void kernel_launch(void* const* d_in, const int* in_sizes, int n_in,
                              void* d_out, int out_size, void* d_ws, size_t ws_size,
                              hipStream_t stream) {
    const float* ue = (const float*)d_in[0];
    const float* ie = (const float*)d_in[1];
    const int* edge = (const int*)d_in[2];
    const int* users = (const int*)d_in[3];
    const int* items = (const int*)d_in[4];

    const int U = in_sizes[0] / LAT;
    const int I = in_sizes[1] / LAT;
    const int N = U + I;
    const int E = in_sizes[2] / 2;
    const int B = in_sizes[3];
    const int* eu = edge;
    const int* ei = edge + E;

    const int nbuk = (N + RB - 1) / RB;                    // 391 for N=100k
    const int cap = ((2 * E / nbuk) * 5 / 4 + 255) & ~255; // ~25% slack

    char* ws = (char*)d_ws;
    size_t off = 0;
    auto alloc = [&](size_t bytes) -> void* {
        void* p = ws + off;
        off += (bytes + 255) & ~(size_t)255;
        return p;
    };
    int*      cnt  = (int*)alloc((size_t)4 * N);
    float*    dinv = (float*)alloc((size_t)4 * N);
    int*      colE = (int*)alloc((size_t)4 * N * ELLC);     // 25.6 MB
    __half*   yA   = (__half*)alloc((size_t)2 * N * LAT);   // 12.8 MB
    __half*   yB   = (__half*)alloc((size_t)2 * N * LAT);
    float*    qacc = (float*)alloc((size_t)4 * 2 * B * LAT);
    unsigned* bbuf = (unsigned*)alloc((size_t)4 * nbuk * cap);  // ~16 MB
    // gcur and ovfc adjacent -> single memset covers both
    size_t zoff = off;
    int*      gcur = (int*)alloc((size_t)4 * nbuk);
    int*      ovfc = (int*)alloc(256);   // [0]=bin spill, [64]=row ovf
    size_t zbytes = off - zoff;
    size_t remain = (ws_size > off + 256) ? (ws_size - off - 256) : 0;
    int ovf_cap = (int)min((size_t)131072, remain / (2 * sizeof(int2)));
    int2* ovf  = (int2*)alloc((size_t)ovf_cap * sizeof(int2));
    int2* rovf = (int2*)alloc((size_t)ovf_cap * sizeof(int2));
    int* rovfc = ovfc + 64;

    hipError_t _e = hipMemsetAsync(gcur, 0, zbytes, stream); (void)_e;

    const int tb = 256;

    // 256 blocks x 1024 thr x RPT 8 = 2.1M >= E undirected edges
    bin_k<<<256, 1024, 0, stream>>>(eu, ei, gcur, bbuf, ovf, ovfc, E, U, nbuk, cap, ovf_cap);
    build_k<<<nbuk, 1024, 0, stream>>>(bbuf, gcur, cnt, colE, dinv, ue, ie, yA,
                                       rovf, rovfc, N, U, cap, ovf_cap);
    fix_k<<<1, 1024, 0, stream>>>(ovf, ovfc, cnt, colE, dinv, ue, ie, yA,
                                  rovf, rovfc, ovf_cap, ovf_cap, U);

    const int wpb = tb / 64;
    int pgrid = (N + 2 * B + wpb - 1) / wpb;   // row waves + fused query waves

    __half* yin = yA;
    __half* yout = yB;
    for (int layer = 0; layer < 4; ++layer) {
        prop_h_k<<<pgrid, tb, 0, stream>>>(cnt, colE, dinv, yin, yout,
                                           users, items, qacc, rovf, rovfc,
                                           ovf_cap, B, U, layer == 0 ? 1 : 0, N);
        __half* tmp = yin; yin = yout; yout = tmp;
    }

    final_k<<<(B + wpb - 1) / wpb, tb, 0, stream>>>(qacc, yin, dinv, users, items,
                                                    (float*)d_out, B, U);
}